// Round 15
// baseline (82.650 us; speedup 1.0000x reference)
//
#include <hip/hip_runtime.h>

// TDT loss, fixed shapes from setup_inputs():
#define TDT_B  8
#define TDT_T  256
#define TDT_U  64
#define TDT_U1 65
#define TDT_V1 513   // V+1, blank index = 512
#define TP     275   // 4 zero-pad slices + 256 + slack
#define SIG    0.05f
#define SHIFT  3.0f  // exponent shift PER TIME-STEP: duration-d weight carries SHIFT*d

// ws layout (floats):
//   WB: float4[B][TP][U1] = exp(lpb + ld_i - SIG + SHIFT*(i+1))
//   WY: float4[B][TP][U]  = exp(lpy + ld_i - SIG + SHIFT*(i+1))
//   GC: float4[B][TP]     = WB[b][tp][u=64]  (compact G column)
#define OFF_PYD 572000                        // 8*275*65*4
#define OFF_GC  1135200                       // + 8*275*64*4; GC = 8800 floats

// Kernel 1: per-(b,t,u) row log-softmax over 513 labels. One wave per row.
// NEW: float4 loads. Row r starts at float offset r*513 ≡ r (mod 4); with
// o = (4 - r%4) & 3, row+o is 16B-aligned. Lane l loads elems o+8l..o+8l+7
// as two float4 (128 float4 total = elems o..o+511). Elements >= 513 (only
// when o>=2; never OOB since rows with o>=2 are never the last row) are
// SWAPPED for front elems [0..o-2] on lane 63; the one remaining element is
// lane 0's 'extra'. Every row element is counted exactly once.
__global__ __launch_bounds__(256) void k_prep(
    const float* __restrict__ la, const float* __restrict__ da,
    const int* __restrict__ tgt, float* __restrict__ ws,
    float* __restrict__ out)
{
  if (blockIdx.x == 0 && threadIdx.x == 0) out[0] = 0.f;

  const int l = threadIdx.x & 63;
  const int r = (blockIdx.x << 2) + (threadIdx.x >> 6);   // row in [0, B*T*U1)
  const int u  = r % TDT_U1;
  const int bt = r / TDT_U1;
  const int t  = bt & (TDT_T - 1);
  const int b  = bt >> 8;

  const float* row = la + (size_t)r * TDT_V1;
  const int o = (4 - (r & 3)) & 3;          // uniform per wave
  const float4* p4 = (const float4*)(row + o);
  float4 va = p4[2 * l];                    // elems o+8l+0..3
  float4 vb = p4[2 * l + 1];                // elems o+8l+4..7

  // front scalars (always in-bounds: rows have >= 3 elements)
  const float f0 = row[0], f1 = row[1], f2 = row[2];

  // lane-63 tail fixups: elems 513 (o>=2) and 514 (o==3) are invalid ->
  // swap in front elems 0 (and 1) so max/sum stay exact
  if (l == 63) {
    if (o == 2)      { vb.w = f0; }
    else if (o == 3) { vb.z = f0; vb.w = f1; }
  }
  // the single element not covered by the vec span / swaps:
  const float extra = (o == 0) ? row[512] : (o == 1) ? f0 : (o == 2) ? f1 : f2;

  float m = fmaxf(fmaxf(fmaxf(va.x, va.y), fmaxf(va.z, va.w)),
                  fmaxf(fmaxf(vb.x, vb.y), fmaxf(vb.z, vb.w)));
  m = fmaxf(m, extra);                      // extra is a valid row element
#pragma unroll
  for (int off = 32; off; off >>= 1) m = fmaxf(m, __shfl_xor(m, off));
  float s = (l == 0) ? __expf(extra - m) : 0.f;
  s += __expf(va.x - m) + __expf(va.y - m) + __expf(va.z - m) + __expf(va.w - m);
  s += __expf(vb.x - m) + __expf(vb.y - m) + __expf(vb.z - m) + __expf(vb.w - m);
#pragma unroll
  for (int off = 32; off; off >>= 1) s += __shfl_xor(s, off);
  const float lse = m + __logf(s);

  // duration log-softmax (uniform per wave)
  const float4 dv = *(const float4*)(da + ((size_t)r << 2));
  const float m4 = fmaxf(fmaxf(dv.x, dv.y), fmaxf(dv.z, dv.w));
  const float l4 = m4 + __logf(__expf(dv.x - m4) + __expf(dv.y - m4) +
                               __expf(dv.z - m4) + __expf(dv.w - m4));
  // per-duration: ld_i - l4 + SHIFT*(i+1)  (scale-consistent exp domain)
  const float d0 = dv.x - l4 + SHIFT * 1.0f;
  const float d1 = dv.y - l4 + SHIFT * 2.0f;
  const float d2 = dv.z - l4 + SHIFT * 3.0f;
  const float d3 = dv.w - l4 + SHIFT * 4.0f;

  float4* WB4 = (float4*)ws;
  float4* WY4 = (float4*)(ws + OFF_PYD);
  float4* GC4 = (float4*)(ws + OFF_GC);
  const int tp = t + 4;

  // blank logit (elem 512): o==0 -> lane0 extra; o==1 -> l63 vb.w;
  // o==2 -> l63 vb.z (pre-fixup value is elem 512, untouched); o==3 -> l63 vb.y
  {
    const int blank_lane = (o == 0) ? 0 : 63;
    const float xb = (o == 0) ? extra : (o == 1) ? vb.w : (o == 2) ? vb.z : vb.y;
    if (l == blank_lane) {
      const float pb = xb - lse - SIG;
      const float4 wb = make_float4(__expf(pb + d0), __expf(pb + d1),
                                    __expf(pb + d2), __expf(pb + d3));
      WB4[(b * TP + tp) * TDT_U1 + u] = wb;
      if (u == TDT_U) GC4[b * TP + tp] = wb;
    }
  }

  // target gather: tg in [0,512). If tg >= o it lives at lane (tg-o)>>3,
  // component (tg-o)&7 (never a swapped slot: swaps only hit elems >= 513).
  // If tg < o (front), lane 0 serves it from f0/f1/f2.
  const int tg = (u < TDT_U) ? tgt[b * TDT_U + u] : -1;
  if (tg >= 0) {
    bool own = false; float vt = 0.f;
    if (tg >= o) {
      const int k = tg - o;
      if (l == (k >> 3)) {
        const float4 vsel = ((k >> 2) & 1) ? vb : va;
        vt = (k & 2) ? ((k & 1) ? vsel.w : vsel.z)
                     : ((k & 1) ? vsel.y : vsel.x);
        own = true;
      }
    } else if (l == 0) {
      vt = (tg == 0) ? f0 : (tg == 1) ? f1 : f2;
      own = true;
    }
    if (own) {
      const float py = vt - lse - SIG;
      WY4[(b * TP + tp) * TDT_U + u] =
          make_float4(__expf(py + d0), __expf(py + d1),
                      __expf(py + d2), __expf(py + d3));
    }
  }

  // zero pads for tau < 0 (slices tp = 0..3): exp(-inf) = 0
  if (t < 4 && l == 0) {
    const float4 z4 = make_float4(0.f, 0.f, 0.f, 0.f);
    WB4[(b * TP + t) * TDT_U1 + u] = z4;
    if (u == TDT_U) GC4[b * TP + t] = z4;
    if (u < TDT_U)  WY4[(b * TP + t) * TDT_U + u] = z4;
  }
}

// DPP wave_shr:1 (ctrl 0x138), bound_ctrl=1 -> lane 0 reads 0. VALU-pipe
// lane shift replacing ds_bpermute on the serial t-chain.
__device__ __forceinline__ float shup1(float x) {
  const int r = __builtin_amdgcn_update_dpp(
      0, __float_as_int(x), 0x138, 0xf, 0xf, true);
  return __int_as_float(r);
}

// v_readlane: SGPR broadcast of one lane's value -- no LDS round-trip
// (replaces __shfl's ds_bpermute on the serial renorm path).
__device__ __forceinline__ float rdlane(float x, int lane) {
  return __int_as_float(__builtin_amdgcn_readlane(__float_as_int(x), lane));
}

// Direct HBM->LDS DMA, 16B/lane: lane l's data lands at ldsbase + l*16.
__device__ __forceinline__ void gl2lds16(const float4* g, float4* lds) {
  __builtin_amdgcn_global_load_lds(
      (const __attribute__((address_space(1))) void*)g,
      (__attribute__((address_space(3))) void*)lds, 16, 0, 0);
}

// Loader helper: fill group j (slices 15j+1 .. 15j+15) into ring third j%3.
// Slice s -> ring slot (s-1)%45; slot holds B[u=0..63] then Y[u=0..63].
__device__ __forceinline__ void fill_group(
    const float4* __restrict__ WB4p, const float4* __restrict__ WY4p,
    float4* ring, int j, int wv, int l)
{
  const int sb = 15 * j + wv;               // this wave's first slice in group
  const int rb = 15 * (j % 3) + (wv - 1);   // its first ring slot
#pragma unroll
  for (int k = 0; k < 5; ++k) {
    const int s    = sb + 3 * k;
    const int slot = rb + 3 * k;
    gl2lds16(WB4p + (size_t)s * TDT_U1 + l, ring + slot * 128);
    gl2lds16(WY4p + (size_t)s * TDT_U  + l, ring + slot * 128 + 64);
  }
}

// Kernel 2: forward DP, exp domain. 8 blocks (one per b) x 4 waves.
// Wave 0: serial chain, depth-15 named register FIFO (lead-12) fed by
// ds_read from the 45-slice LDS ring; issue-bound, so the step is written
// with fmaf and a shared P-sum (14 math ops + 1 DPP). Renorm probes use
// v_readlane (no LDS). Waves 1-3: global_load_lds-stream one group ahead.
__global__ __launch_bounds__(256, 1) void k_dp(
    const float* __restrict__ ws, float* __restrict__ out)
{
  const int b  = blockIdx.x;
  const int wv = threadIdx.x >> 6;
  const int l  = threadIdx.x & 63;
  const float4* WB4p = (const float4*)ws + (size_t)b * (TP * TDT_U1);
  const float4* WY4p = (const float4*)(ws + OFF_PYD) + (size_t)b * (TP * TDT_U);
  const float4* GC4p = (const float4*)(ws + OFF_GC) + (size_t)b * TP;

  extern __shared__ float4 smem[];          // 45*128 ring + 275 G = 96.6 KB
  float4* ring = smem;
  float4* glds = smem + 45 * 128;

  // prologue: G column (lane-variant vector loads) + groups 0,1
  if (wv != 0) {
    for (int i = (threadIdx.x - 64); i < TP; i += 192) glds[i] = GC4p[i];
    fill_group(WB4p, WY4p, ring, 0, wv, l);
    fill_group(WB4p, WY4p, ring, 1, wv, l);
  }
  __syncthreads();

  // depth-15 FIFO: slot(s) = s%15 holds slice s
  float4 B0,B1,B2,B3,B4,B5,B6,B7,B8,B9,B10,B11,B12,B13,B14;
  float4 Y0,Y1,Y2,Y3,Y4,Y5,Y6,Y7,Y8,Y9,Y10,Y11,Y12,Y13,Y14;
  float4 G0,G1,G2,G3,G4,G5,G6,G7,G8,G9,G10,G11,G12,G13,G14;
  float a1 = 0.f, a2 = 0.f, a3 = 0.f, a4 = 0.f;
  float c1 = 0.f, c2 = 0.f, c3 = 0.f, c4 = 0.f;
  float L = 0.f;

#define LOADSLOT(S, RS, TPI) do {            \
    const int _r = (RS) * 128;               \
    B##S = ring[_r + l];                     \
    Y##S = ring[_r + 64 + l];                \
    G##S = glds[TPI];                        \
  } while (0)

  if (wv == 0) {
    // preload slices 1..15 (ring slots 0..14, third 0) into FIFO slot s%15
    LOADSLOT(1, 0, 1);   LOADSLOT(2, 1, 2);   LOADSLOT(3, 2, 3);
    LOADSLOT(4, 3, 4);   LOADSLOT(5, 4, 5);   LOADSLOT(6, 5, 6);
    LOADSLOT(7, 6, 7);   LOADSLOT(8, 7, 8);   LOADSLOT(9, 8, 9);
    LOADSLOT(10, 9, 10); LOADSLOT(11, 10, 11);LOADSLOT(12, 11, 12);
    LOADSLOT(13, 12, 13);LOADSLOT(14, 13, 14);LOADSLOT(0, 14, 15);
    a1 = (l == 0) ? 1.f : 0.f;               // A = exp(alpha + SHIFT*t - L)
  }

  // step t: FIFO slots (t+3)%15..t%15 supply slices t+3..t; then load slice
  // t+15 from ring slot (t+14)%45 into FIFO slot t%15 (=S3). Lead-12.
  // P = sum of label terms (shared by shift and c-column); fma pairs.
#define STEP(S0,S1,S2,S3, RSL, TPI) do {                                     \
    float p01 = fmaf(a2, Y##S1.y, a1 * Y##S0.x);                             \
    float p23 = fmaf(a4, Y##S3.w, a3 * Y##S2.z);                             \
    float P   = p01 + p23;                                                   \
    float m   = shup1(P);                                                    \
    float b01 = fmaf(a2, B##S1.y, a1 * B##S0.x);                             \
    float b23 = fmaf(a4, B##S3.w, a3 * B##S2.z);                             \
    float q01 = fmaf(c2, G##S1.y, c1 * G##S0.x);                             \
    float q23 = fmaf(c4, G##S3.w, c3 * G##S2.z);                             \
    float anew = (b01 + b23) + m;                                            \
    float cnew = (q01 + q23) + P;                                            \
    a4 = a3; a3 = a2; a2 = a1; a1 = anew;                                    \
    c4 = c3; c3 = c2; c2 = c1; c1 = cnew;                                    \
    LOADSLOT(S3, RSL, TPI);                                                  \
  } while (0)

  for (int i = 0, tb = 1; i < 17; ++i, tb += 15) {
    __syncthreads();
    if (wv != 0) {
      if (i < 16) fill_group(WB4p, WY4p, ring, i + 2, wv, l);
    } else {
      const int rbB = 15 * ((i + 1) % 3);    // third holding group i+1
      if (i) {
        // uniform renorm: 1/max(two band probes); bookkeeping in L
        const float r1 = rdlane(a1, tb >> 3);
        const float r2 = rdlane(a1, tb >> 2);
        const float rl = fmaxf(r1, r2);
        const float sc = (rl > 1e-30f) ? (1.0f / rl) : 1.0f;
        L -= __logf(sc);
        a1 *= sc; a2 *= sc; a3 *= sc; a4 *= sc;
        c1 *= sc; c2 *= sc; c3 *= sc; c4 *= sc;
      }
      // tb%15 == 1 always; loads pull slices tb+15..tb+29 (group i+1) from
      // ring slots rbB+0..14 (filled during iteration i-1)
      STEP(4,3,2,1,     rbB + 0,  tb + 15);
      STEP(5,4,3,2,     rbB + 1,  tb + 16);
      STEP(6,5,4,3,     rbB + 2,  tb + 17);
      STEP(7,6,5,4,     rbB + 3,  tb + 18);
      STEP(8,7,6,5,     rbB + 4,  tb + 19);
      STEP(9,8,7,6,     rbB + 5,  tb + 20);
      STEP(10,9,8,7,    rbB + 6,  tb + 21);
      STEP(11,10,9,8,   rbB + 7,  tb + 22);
      STEP(12,11,10,9,  rbB + 8,  tb + 23);
      STEP(13,12,11,10, rbB + 9,  tb + 24);
      STEP(14,13,12,11, rbB + 10, tb + 25);
      STEP(0,14,13,12,  rbB + 11, tb + 26);
      STEP(1,0,14,13,   rbB + 12, tb + 27);
      STEP(2,1,0,14,    rbB + 13, tb + 28);
      STEP(3,2,1,0,     rbB + 14, tb + 29);
    }
  }

  if (wv == 0 && l == 63) {
    // ll = L - SHIFT*256 + log( sum_d C[256-d] * WG_d ); G from LDS glds[tp]
    const float sum = c1 * glds[259].x
                    + c2 * glds[258].y
                    + c3 * glds[257].z
                    + c4 * glds[256].w;
    const float ll = L - SHIFT * 256.0f + __logf(sum);
    atomicAdd(out, ll * (-1.0f / TDT_B));
  }
#undef STEP
#undef LOADSLOT
}

extern "C" void kernel_launch(void* const* d_in, const int* in_sizes, int n_in,
                              void* d_out, int out_size, void* d_ws, size_t ws_size,
                              hipStream_t stream)
{
  const float* la = (const float*)d_in[0];   // label_acts    (B,T,U+1,V+1) f32
  const float* da = (const float*)d_in[1];   // duration_acts (B,T,U+1,D)   f32
  const int*   tg = (const int*)d_in[2];     // targets       (B,U)         i32
  float* ws  = (float*)d_ws;
  float* out = (float*)d_out;

  const int rows = TDT_B * TDT_T * TDT_U1;   // 133120
  k_prep<<<rows / 4, 256, 0, stream>>>(la, da, tg, ws, out);
  k_dp  <<<TDT_B, 256, (45 * 128 + TP) * sizeof(float4), stream>>>(ws, out);
}